// Round 4
// baseline (678.346 us; speedup 1.0000x reference)
//
#include <hip/hip_runtime.h>
#include <hip/hip_bf16.h>

#define S_LEN 2048
#define DMODEL 1024
#define NHEAD 16
#define HD 64

typedef short short8 __attribute__((ext_vector_type(8)));
typedef short short4_t __attribute__((ext_vector_type(4)));
typedef float f32x4 __attribute__((ext_vector_type(4)));

// fp32 -> bf16 (RNE) bit-level, no header dependence
__device__ inline unsigned short f2bf(float f) {
    union { float f; unsigned int u; } c;
    c.f = f;
    unsigned int r = c.u + 0x7fffu + ((c.u >> 16) & 1u);
    return (unsigned short)(r >> 16);
}

// ---------------------------------------------------------------------------
// Bulk cast fp32 -> bf16, 8 elems/thread, vectorized 2x float4 -> short8
// ---------------------------------------------------------------------------
__global__ __launch_bounds__(256) void cast_f32_bf16(
    const float* __restrict__ in, short* __restrict__ out, int n8)
{
    int i = blockIdx.x * 256 + threadIdx.x;
    if (i < n8) {
        float4 a = ((const float4*)in)[2 * i];
        float4 b = ((const float4*)in)[2 * i + 1];
        short8 o;
        o[0] = (short)f2bf(a.x); o[1] = (short)f2bf(a.y);
        o[2] = (short)f2bf(a.z); o[3] = (short)f2bf(a.w);
        o[4] = (short)f2bf(b.x); o[5] = (short)f2bf(b.y);
        o[6] = (short)f2bf(b.z); o[7] = (short)f2bf(b.w);
        ((short8*)out)[i] = o;
    }
}

// ---------------------------------------------------------------------------
// bf16 MFMA GEMM: C[M,N] = A[M,K](bf16) @ W[N,K](bf16)^T + bias(f32)
// BM=BN=128, BK=64, 256 threads = 4 waves in 2x2; each wave owns a 64x64
// output sub-tile = 4x4 grid of 16x16x32 MFMA fragments, fp32 accum.
// A/B fragments: lane l&15 = m (or n); k-elements = contiguous 8 at
// kk*32 + (l>>4)*8 — a bijective k-permutation applied identically to both
// operands, so the MFMA dot-product is layout-exact regardless of the HW
// k-mapping (A/B maps are mirror-symmetric for 16x16 shapes).
// C/D mapping (HW-verified m89/m91): col=lane&15, row=(lane>>4)*4+reg.
// QKV=true: scatter fp32 output into q/k/v workspace laid out [B,H,S,hd].
// ---------------------------------------------------------------------------
template<bool QKV>
__global__ __launch_bounds__(256) void gemm_mfma(
    const short* __restrict__ A, const short* __restrict__ W,
    const float* __restrict__ bias, float* __restrict__ C,
    int N, int K,
    float* __restrict__ qo, float* __restrict__ ko, float* __restrict__ vo)
{
    __shared__ short Ash[128 * 64];   // [row][k] row-major, 16 KB
    __shared__ short Bsh[128 * 64];   // [n-row][k] row-major, 16 KB

    const int tid = threadIdx.x;
    const int l = tid & 63;
    const int wid = tid >> 6;
    const int wr = wid >> 1, wc = wid & 1;      // 2x2 wave grid
    const int n0 = blockIdx.x << 7, m0 = blockIdx.y << 7;

    const short* Abase = A + (size_t)m0 * K;
    const short* Wbase = W + (size_t)n0 * K;

    f32x4 acc[4][4];
    #pragma unroll
    for (int i = 0; i < 4; ++i)
        #pragma unroll
        for (int j = 0; j < 4; ++j)
            acc[i][j] = (f32x4)0.0f;

    short8 sa[4], sb[4];
    int rrow[4], rcol[4];
    #pragma unroll
    for (int i = 0; i < 4; ++i) {
        int chunk = i * 256 + tid;      // 1024 chunks cover 128x64 shorts
        rrow[i] = chunk >> 3;
        rcol[i] = (chunk & 7) << 3;
    }

    // prologue: load K-tile 0 to registers
    #pragma unroll
    for (int i = 0; i < 4; ++i) {
        sa[i] = *(const short8*)(Abase + (size_t)rrow[i] * K + rcol[i]);
        sb[i] = *(const short8*)(Wbase + (size_t)rrow[i] * K + rcol[i]);
    }

    const int NT = K >> 6;   // 16 K-tiles
    for (int kt = 0; kt < NT; ++kt) {
        __syncthreads();   // previous compute done reading LDS
        #pragma unroll
        for (int i = 0; i < 4; ++i) {
            *(short8*)&Ash[rrow[i] * 64 + rcol[i]] = sa[i];
            *(short8*)&Bsh[rrow[i] * 64 + rcol[i]] = sb[i];
        }
        __syncthreads();
        // prefetch next K-tile to registers while computing this one
        if (kt + 1 < NT) {
            const int k0 = (kt + 1) << 6;
            #pragma unroll
            for (int i = 0; i < 4; ++i) {
                sa[i] = *(const short8*)(Abase + (size_t)rrow[i] * K + k0 + rcol[i]);
                sb[i] = *(const short8*)(Wbase + (size_t)rrow[i] * K + k0 + rcol[i]);
            }
        }
        // 2 x (8 ds_read_b128 + 16 MFMA)
        #pragma unroll
        for (int kk = 0; kk < 2; ++kk) {
            short8 af[4], bf[4];
            const int kof = kk * 32 + ((l >> 4) << 3);
            #pragma unroll
            for (int mi = 0; mi < 4; ++mi)
                af[mi] = *(const short8*)&Ash[(wr * 64 + mi * 16 + (l & 15)) * 64 + kof];
            #pragma unroll
            for (int ni = 0; ni < 4; ++ni)
                bf[ni] = *(const short8*)&Bsh[(wc * 64 + ni * 16 + (l & 15)) * 64 + kof];
            #pragma unroll
            for (int mi = 0; mi < 4; ++mi)
                #pragma unroll
                for (int ni = 0; ni < 4; ++ni)
                    acc[mi][ni] = __builtin_amdgcn_mfma_f32_16x16x32_bf16(
                        af[mi], bf[ni], acc[mi][ni], 0, 0, 0);
        }
    }

    // epilogue
    #pragma unroll
    for (int ni = 0; ni < 4; ++ni) {
        const int col = n0 + wc * 64 + ni * 16 + (l & 15);
        const float bv = bias[col];
        if (QKV) {
            const int part = col >> 10;
            const int h = (col >> 6) & 15;
            const int e = col & 63;
            float* __restrict__ dst = part == 0 ? qo : (part == 1 ? ko : vo);
            #pragma unroll
            for (int mi = 0; mi < 4; ++mi) {
                #pragma unroll
                for (int r = 0; r < 4; ++r) {
                    int row = m0 + wr * 64 + mi * 16 + ((l >> 4) << 2) + r;
                    int b = row >> 11, s = row & (S_LEN - 1);
                    dst[(((size_t)(b * NHEAD + h) * S_LEN + s) << 6) + e] =
                        acc[mi][ni][r] + bv;
                }
            }
        } else {
            #pragma unroll
            for (int mi = 0; mi < 4; ++mi) {
                #pragma unroll
                for (int r = 0; r < 4; ++r) {
                    int row = m0 + wr * 64 + mi * 16 + ((l >> 4) << 2) + r;
                    C[(size_t)row * N + col] = acc[mi][ni][r] + bv;
                }
            }
        }
    }
}

// ---------------------------------------------------------------------------
// Flash attention, fp32, causal — structure desk-checked (round 0).
// One block = one (b,h, 64-row q-tile); 256 threads; ty=4 q-rows, tx=4 cols.
// Online softmax state replicated across 16-lane row groups (__shfl_xor w16).
// Output written directly as bf16 into yb [B,S,D] for the bf16 proj GEMM.
// ---------------------------------------------------------------------------
__global__ __launch_bounds__(256) void flash_attn(
    const float* __restrict__ q, const float* __restrict__ k,
    const float* __restrict__ v, short* __restrict__ yb)
{
    __shared__ float Qs[HD][68];   // [kk][q]  (transposed)
    __shared__ float Ks[HD][68];   // [kk][k]  (transposed)
    __shared__ float Vs[64][68];   // [k][e]
    __shared__ float Ps[64][68];   // [k][q]  (transposed)

    const int tid = threadIdx.x;
    const int tx = tid & 15, ty = tid >> 4;
    const int qt = blockIdx.x & 31;
    const int bh = blockIdx.x >> 5;
    const size_t base = (size_t)bh * S_LEN * HD;
    const int q0 = qt << 6;

    #pragma unroll
    for (int i = 0; i < 4; ++i) {
        int idx = i * 256 + tid;
        int row = idx >> 4, col = (idx & 15) << 2;
        float4 t4 = *(const float4*)&q[base + (size_t)(q0 + row) * HD + col];
        Qs[col + 0][row] = t4.x; Qs[col + 1][row] = t4.y;
        Qs[col + 2][row] = t4.z; Qs[col + 3][row] = t4.w;
    }

    float O[4][4] = {};
    float mrow[4], lrow[4];
    #pragma unroll
    for (int i = 0; i < 4; ++i) { mrow[i] = -1e30f; lrow[i] = 0.0f; }

    __syncthreads();

    for (int t = 0; t <= qt; ++t) {
        const int k0 = t << 6;
        #pragma unroll
        for (int i = 0; i < 4; ++i) {
            int idx = i * 256 + tid;
            int row = idx >> 4, col = (idx & 15) << 2;
            float4 kv = *(const float4*)&k[base + (size_t)(k0 + row) * HD + col];
            Ks[col + 0][row] = kv.x; Ks[col + 1][row] = kv.y;
            Ks[col + 2][row] = kv.z; Ks[col + 3][row] = kv.w;
            float4 vv = *(const float4*)&v[base + (size_t)(k0 + row) * HD + col];
            *(float4*)&Vs[row][col] = vv;
        }
        __syncthreads();

        float s[4][4] = {};
        #pragma unroll 8
        for (int kk = 0; kk < HD; ++kk) {
            float4 a = *(const float4*)&Qs[kk][ty << 2];
            float4 b = *(const float4*)&Ks[kk][tx << 2];
            float ar[4] = {a.x, a.y, a.z, a.w};
            float br[4] = {b.x, b.y, b.z, b.w};
            #pragma unroll
            for (int i = 0; i < 4; ++i)
                #pragma unroll
                for (int j = 0; j < 4; ++j)
                    s[i][j] = fmaf(ar[i], br[j], s[i][j]);
        }

        const bool diag = (t == qt);
        #pragma unroll
        for (int i = 0; i < 4; ++i)
            #pragma unroll
            for (int j = 0; j < 4; ++j) {
                s[i][j] *= 0.125f;   // 1/sqrt(64)
                if (diag && (k0 + (tx << 2) + j > q0 + (ty << 2) + i))
                    s[i][j] = -1e30f;
            }

        #pragma unroll
        for (int i = 0; i < 4; ++i) {
            float mx = fmaxf(fmaxf(s[i][0], s[i][1]), fmaxf(s[i][2], s[i][3]));
            mx = fmaxf(mx, __shfl_xor(mx, 1, 16));
            mx = fmaxf(mx, __shfl_xor(mx, 2, 16));
            mx = fmaxf(mx, __shfl_xor(mx, 4, 16));
            mx = fmaxf(mx, __shfl_xor(mx, 8, 16));
            float mnew = fmaxf(mrow[i], mx);
            float alpha = __expf(mrow[i] - mnew);
            mrow[i] = mnew;
            float rs = 0.0f;
            #pragma unroll
            for (int j = 0; j < 4; ++j) {
                s[i][j] = __expf(s[i][j] - mnew);
                rs += s[i][j];
            }
            rs += __shfl_xor(rs, 1, 16);
            rs += __shfl_xor(rs, 2, 16);
            rs += __shfl_xor(rs, 4, 16);
            rs += __shfl_xor(rs, 8, 16);
            lrow[i] = lrow[i] * alpha + rs;
            #pragma unroll
            for (int j = 0; j < 4; ++j) O[i][j] *= alpha;
        }

        #pragma unroll
        for (int i = 0; i < 4; ++i)
            #pragma unroll
            for (int j = 0; j < 4; ++j)
                Ps[(tx << 2) + j][(ty << 2) + i] = s[i][j];
        __syncthreads();

        #pragma unroll 8
        for (int kk = 0; kk < 64; ++kk) {
            float4 p = *(const float4*)&Ps[kk][ty << 2];
            float4 vv = *(const float4*)&Vs[kk][tx << 2];
            float pr[4] = {p.x, p.y, p.z, p.w};
            float vr[4] = {vv.x, vv.y, vv.z, vv.w};
            #pragma unroll
            for (int i = 0; i < 4; ++i)
                #pragma unroll
                for (int j = 0; j < 4; ++j)
                    O[i][j] = fmaf(pr[i], vr[j], O[i][j]);
        }
        __syncthreads();
    }

    // epilogue: normalize and write bf16 y in [B,S,D] layout
    const int b = bh >> 4, h = bh & 15;
    #pragma unroll
    for (int i = 0; i < 4; ++i) {
        int qrow = q0 + (ty << 2) + i;
        float inv = 1.0f / lrow[i];
        short4_t o;
        o[0] = (short)f2bf(O[i][0] * inv);
        o[1] = (short)f2bf(O[i][1] * inv);
        o[2] = (short)f2bf(O[i][2] * inv);
        o[3] = (short)f2bf(O[i][3] * inv);
        *(short4_t*)&yb[((size_t)b * S_LEN + qrow) * DMODEL + h * HD + (tx << 2)] = o;
    }
}

// ---------------------------------------------------------------------------
// Workspace liveness plan (62 MB peak, all offsets from ws base in bytes):
//   [ 0,16M)  qw (fp32)      live: gemm1 -> attn
//   [16,32M)  kw (fp32)      live: gemm1 -> attn
//   [32,48M)  vw (fp32)      live: gemm1 -> attn
//   [48,56M)  xb (bf16)      live: cast -> gemm1   } same region,
//   [48,56M)  yb (bf16)      live: attn -> gemm2   } disjoint in time
//   [56,62M)  wab (bf16)     live: cast -> gemm1   } same region,
//   [56,58M)  wpb (bf16)     live: cast(after g1) -> gemm2 } disjoint in time
// ---------------------------------------------------------------------------
extern "C" void kernel_launch(void* const* d_in, const int* in_sizes, int n_in,
                              void* d_out, int out_size, void* d_ws, size_t ws_size,
                              hipStream_t stream) {
    const float* x      = (const float*)d_in[0];   // [2,2048,1024]
    const float* w_attn = (const float*)d_in[1];   // [3072,1024]
    const float* b_attn = (const float*)d_in[2];   // [3072]
    const float* w_proj = (const float*)d_in[3];   // [1024,1024]
    const float* b_proj = (const float*)d_in[4];   // [1024]
    float* out = (float*)d_out;                    // [2,2048,1024]

    const int B = 2;
    const int M = B * S_LEN;                                   // 4096
    const size_t qkv_elems = (size_t)B * NHEAD * S_LEN * HD;   // 4,194,304
    const size_t x_elems  = (size_t)M * DMODEL;                // 4,194,304
    const size_t wa_elems = (size_t)3 * DMODEL * DMODEL;       // 3,145,728
    const size_t wp_elems = (size_t)DMODEL * DMODEL;           // 1,048,576

    char* wsb = (char*)d_ws;
    float* qw  = (float*)(wsb);
    float* kw  = (float*)(wsb + (16u << 20));
    float* vw  = (float*)(wsb + (32u << 20));
    short* xb  = (short*)(wsb + (48u << 20));
    short* yb  = (short*)(wsb + (48u << 20));
    short* wab = (short*)(wsb + (56u << 20));
    short* wpb = (short*)(wsb + (56u << 20));

    // 0) casts to bf16 (GEMM-1 operands)
    cast_f32_bf16<<<dim3((int)(x_elems  / 8 / 256)), 256, 0, stream>>>(x, xb, (int)(x_elems / 8));
    cast_f32_bf16<<<dim3((int)(wa_elems / 8 / 256)), 256, 0, stream>>>(w_attn, wab, (int)(wa_elems / 8));

    // 1) QKV projection (bf16 MFMA), scatter fp32 to [B,H,S,hd]
    dim3 g1(3 * DMODEL / 128, M / 128);
    gemm_mfma<true><<<g1, 256, 0, stream>>>(xb, wab, b_attn, nullptr,
                                            3 * DMODEL, DMODEL, qw, kw, vw);

    // 1b) cast w_proj (into wab's region — wab dead after gemm1)
    cast_f32_bf16<<<dim3((int)(wp_elems / 8 / 256)), 256, 0, stream>>>(w_proj, wpb, (int)(wp_elems / 8));

    // 2) causal flash attention (fp32 compute) -> yb bf16 [B,S,D]
    //    (yb overwrites xb — dead after gemm1)
    flash_attn<<<dim3(B * NHEAD * (S_LEN / 64)), 256, 0, stream>>>(qw, kw, vw, yb);

    // 3) output projection (bf16 MFMA) -> fp32 out
    dim3 g3(DMODEL / 128, M / 128);
    gemm_mfma<false><<<g3, 256, 0, stream>>>(yb, wpb, b_proj, out,
                                             DMODEL, DMODEL,
                                             nullptr, nullptr, nullptr);
}

// Round 5
// 279.313 us; speedup vs baseline: 2.4286x; 2.4286x over previous
//
#include <hip/hip_runtime.h>
#include <hip/hip_bf16.h>

#define S_LEN 2048
#define DMODEL 1024
#define NHEAD 16
#define HD 64

typedef short short8 __attribute__((ext_vector_type(8)));
typedef float f32x4 __attribute__((ext_vector_type(4)));

// fp32 -> bf16 (RNE) bit-level
__device__ inline unsigned short f2bf(float f) {
    union { float f; unsigned int u; } c;
    c.f = f;
    unsigned int r = c.u + 0x7fffu + ((c.u >> 16) & 1u);
    return (unsigned short)(r >> 16);
}

// ---------------------------------------------------------------------------
// Bulk cast fp32 -> bf16
// ---------------------------------------------------------------------------
__global__ __launch_bounds__(256) void cast_f32_bf16(
    const float* __restrict__ in, short* __restrict__ out, int n8)
{
    int i = blockIdx.x * 256 + threadIdx.x;
    if (i < n8) {
        float4 a = ((const float4*)in)[2 * i];
        float4 b = ((const float4*)in)[2 * i + 1];
        short8 o;
        o[0] = (short)f2bf(a.x); o[1] = (short)f2bf(a.y);
        o[2] = (short)f2bf(a.z); o[3] = (short)f2bf(a.w);
        o[4] = (short)f2bf(b.x); o[5] = (short)f2bf(b.y);
        o[6] = (short)f2bf(b.z); o[7] = (short)f2bf(b.w);
        ((short8*)out)[i] = o;
    }
}

// ---------------------------------------------------------------------------
// bf16 MFMA GEMM (validated round 4): C = A @ W^T + bias.
// BM=BN=128, BK=64, 4 waves 2x2, 4x4 16x16x32 fragments per wave.
// A/B k-slots use identical bijection g(h,j)=h*8+j (permutation-invariant).
// C/D mapping (HW-verified): col=lane&15, row=(lane>>4)*4+reg.
// QKV=true: emit bf16 q/k ([B,H,S,hd]) and TRANSPOSED v ([B,H,hd,S]).
// ---------------------------------------------------------------------------
template<bool QKV>
__global__ __launch_bounds__(256) void gemm_mfma(
    const short* __restrict__ A, const short* __restrict__ W,
    const float* __restrict__ bias, float* __restrict__ C,
    int N, int K,
    short* __restrict__ qo, short* __restrict__ ko, short* __restrict__ vo)
{
    __shared__ __align__(16) short Ash[128 * 64];
    __shared__ __align__(16) short Bsh[128 * 64];

    const int tid = threadIdx.x;
    const int l = tid & 63;
    const int wid = tid >> 6;
    const int wr = wid >> 1, wc = wid & 1;
    const int n0 = blockIdx.x << 7, m0 = blockIdx.y << 7;

    const short* Abase = A + (size_t)m0 * K;
    const short* Wbase = W + (size_t)n0 * K;

    f32x4 acc[4][4];
    #pragma unroll
    for (int i = 0; i < 4; ++i)
        #pragma unroll
        for (int j = 0; j < 4; ++j)
            acc[i][j] = (f32x4)0.0f;

    short8 sa[4], sb[4];
    int rrow[4], rcol[4];
    #pragma unroll
    for (int i = 0; i < 4; ++i) {
        int chunk = i * 256 + tid;
        rrow[i] = chunk >> 3;
        rcol[i] = (chunk & 7) << 3;
    }

    #pragma unroll
    for (int i = 0; i < 4; ++i) {
        sa[i] = *(const short8*)(Abase + (size_t)rrow[i] * K + rcol[i]);
        sb[i] = *(const short8*)(Wbase + (size_t)rrow[i] * K + rcol[i]);
    }

    const int NT = K >> 6;
    for (int kt = 0; kt < NT; ++kt) {
        __syncthreads();
        #pragma unroll
        for (int i = 0; i < 4; ++i) {
            *(short8*)&Ash[rrow[i] * 64 + rcol[i]] = sa[i];
            *(short8*)&Bsh[rrow[i] * 64 + rcol[i]] = sb[i];
        }
        __syncthreads();
        if (kt + 1 < NT) {
            const int k0 = (kt + 1) << 6;
            #pragma unroll
            for (int i = 0; i < 4; ++i) {
                sa[i] = *(const short8*)(Abase + (size_t)rrow[i] * K + k0 + rcol[i]);
                sb[i] = *(const short8*)(Wbase + (size_t)rrow[i] * K + k0 + rcol[i]);
            }
        }
        #pragma unroll
        for (int kk = 0; kk < 2; ++kk) {
            short8 af[4], bf[4];
            const int kof = kk * 32 + ((l >> 4) << 3);
            #pragma unroll
            for (int mi = 0; mi < 4; ++mi)
                af[mi] = *(const short8*)&Ash[(wr * 64 + mi * 16 + (l & 15)) * 64 + kof];
            #pragma unroll
            for (int ni = 0; ni < 4; ++ni)
                bf[ni] = *(const short8*)&Bsh[(wc * 64 + ni * 16 + (l & 15)) * 64 + kof];
            #pragma unroll
            for (int mi = 0; mi < 4; ++mi)
                #pragma unroll
                for (int ni = 0; ni < 4; ++ni)
                    acc[mi][ni] = __builtin_amdgcn_mfma_f32_16x16x32_bf16(
                        af[mi], bf[ni], acc[mi][ni], 0, 0, 0);
        }
    }

    #pragma unroll
    for (int ni = 0; ni < 4; ++ni) {
        const int col = n0 + wc * 64 + ni * 16 + (l & 15);
        const float bv = bias[col];
        if (QKV) {
            const int part = col >> 10;
            const int h = (col >> 6) & 15;
            const int e = col & 63;
            #pragma unroll
            for (int mi = 0; mi < 4; ++mi) {
                #pragma unroll
                for (int r = 0; r < 4; ++r) {
                    int row = m0 + wr * 64 + mi * 16 + ((l >> 4) << 2) + r;
                    int b = row >> 11, s = row & (S_LEN - 1);
                    short bf = (short)f2bf(acc[mi][ni][r] + bv);
                    if (part == 0)
                        qo[((size_t)(b * NHEAD + h) * S_LEN + s) * HD + e] = bf;
                    else if (part == 1)
                        ko[((size_t)(b * NHEAD + h) * S_LEN + s) * HD + e] = bf;
                    else  // v stored transposed: [B,H,e,S]
                        vo[((size_t)(b * NHEAD + h) * HD + e) * S_LEN + s] = bf;
                }
            }
        } else {
            #pragma unroll
            for (int mi = 0; mi < 4; ++mi) {
                #pragma unroll
                for (int r = 0; r < 4; ++r) {
                    int row = m0 + wr * 64 + mi * 16 + ((l >> 4) << 2) + r;
                    C[(size_t)row * N + col] = acc[mi][ni][r] + bv;
                }
            }
        }
    }
}

// ---------------------------------------------------------------------------
// MFMA flash attention, causal, bf16 inputs / fp32 softmax+accum.
// Block = 64 q-rows of one (b,h); 4 waves, wave w owns q-rows w*16..w*16+15.
// KV tiles of 64 keys; K,V(transposed) staged in XOR-swizzled LDS
// (16B slot ^= row&7 within 128B rows -> b128 reads at bandwidth floor).
// P converted bf16 via wave-private swizzled LDS strip (no extra barrier).
// Fragment k-slots use the same g(h,j)=h*8+j on both operands of each MFMA.
// ---------------------------------------------------------------------------
__global__ __launch_bounds__(256) void flash_attn_mfma(
    const short* __restrict__ q, const short* __restrict__ k,
    const short* __restrict__ vt, short* __restrict__ yb)
{
    __shared__ __align__(16) short Ks[64 * 64];   // [key][kdim] swizzled, 8 KB
    __shared__ __align__(16) short Vs[64 * 64];   // [e][key]  swizzled, 8 KB
    __shared__ __align__(16) short Ps[4 * 16 * 64]; // per-wave [q][key] swizzled

    const int tid = threadIdx.x;
    const int l = tid & 63;
    const int w = tid >> 6;
    const int h4 = l >> 4;          // 0..3
    const int c15 = l & 15;         // 0..15
    const int qt = blockIdx.x & 31;
    const int bh = blockIdx.x >> 5;
    const int q0 = qt << 6;

    const size_t kbase = (size_t)bh * S_LEN * HD;   // q,k: [bh][s][e]
    const size_t vbase = (size_t)bh * HD * S_LEN;   // vt:  [bh][e][s]

    // Q fragments held in registers for the whole KV loop
    short8 qf[2];
    {
        const short* qrow = q + kbase + (size_t)(q0 + w * 16 + c15) * HD;
        qf[0] = *(const short8*)(qrow + (h4 << 3));
        qf[1] = *(const short8*)(qrow + 32 + (h4 << 3));
    }

    f32x4 accO[4];                  // O[row=h4*4+r][e=et*16+c15]
    #pragma unroll
    for (int i = 0; i < 4; ++i) accO[i] = (f32x4)0.0f;
    float mrow[4], lrow[4];
    #pragma unroll
    for (int r = 0; r < 4; ++r) { mrow[r] = -1e30f; lrow[r] = 0.0f; }

    // staging coords: thread covers rows srow0, srow0+32; 8-short chunk scol
    const int srow0 = tid >> 3;     // 0..31
    const int scol = tid & 7;       // 0..7

    short8 kreg[2], vreg[2];
    #pragma unroll
    for (int p = 0; p < 2; ++p) {
        kreg[p] = *(const short8*)(k + kbase + (size_t)(srow0 + p * 32) * HD + scol * 8);
        vreg[p] = *(const short8*)(vt + vbase + (size_t)(srow0 + p * 32) * S_LEN + scol * 8);
    }

    short* pws = &Ps[w * 16 * 64];
    const int ntiles = qt + 1;

    for (int t = 0; t < ntiles; ++t) {
        __syncthreads();            // previous tile's LDS reads complete
        #pragma unroll
        for (int p = 0; p < 2; ++p) {
            const int row = srow0 + p * 32;
            const int sc = (scol ^ (row & 7)) << 3;
            *(short8*)&Ks[row * 64 + sc] = kreg[p];
            *(short8*)&Vs[row * 64 + sc] = vreg[p];
        }
        __syncthreads();            // tile visible to all waves
        if (t + 1 < ntiles) {
            const int kn = (t + 1) << 6;
            #pragma unroll
            for (int p = 0; p < 2; ++p) {
                kreg[p] = *(const short8*)(k + kbase + (size_t)(kn + srow0 + p * 32) * HD + scol * 8);
                vreg[p] = *(const short8*)(vt + vbase + (size_t)(srow0 + p * 32) * S_LEN + kn + scol * 8);
            }
        }

        // ---- S = Q K^T : S[q=h4*4+r][key=nt*16+c15]
        f32x4 sacc[4];
        #pragma unroll
        for (int nt = 0; nt < 4; ++nt) sacc[nt] = (f32x4)0.0f;
        #pragma unroll
        for (int c = 0; c < 2; ++c) {
            const int kof = (c << 5) + (h4 << 3);
            #pragma unroll
            for (int nt = 0; nt < 4; ++nt) {
                const int key = nt * 16 + c15;
                const short8 bf = *(const short8*)&Ks[key * 64 + (kof ^ ((key & 7) << 3))];
                sacc[nt] = __builtin_amdgcn_mfma_f32_16x16x32_bf16(qf[c], bf, sacc[nt], 0, 0, 0);
            }
        }

        // ---- scale + causal mask (diag tile only)
        float s[4][4];
        const bool diag = (t == qt);
        #pragma unroll
        for (int nt = 0; nt < 4; ++nt)
            #pragma unroll
            for (int r = 0; r < 4; ++r) {
                float v = sacc[nt][r] * 0.125f;   // 1/sqrt(64)
                if (diag && (nt * 16 + c15 > w * 16 + (h4 << 2) + r))
                    v = -1e30f;
                s[nt][r] = v;
            }

        // ---- online softmax per q-row (16-lane groups share h4)
        #pragma unroll
        for (int r = 0; r < 4; ++r) {
            float mx = fmaxf(fmaxf(s[0][r], s[1][r]), fmaxf(s[2][r], s[3][r]));
            mx = fmaxf(mx, __shfl_xor(mx, 1, 16));
            mx = fmaxf(mx, __shfl_xor(mx, 2, 16));
            mx = fmaxf(mx, __shfl_xor(mx, 4, 16));
            mx = fmaxf(mx, __shfl_xor(mx, 8, 16));
            const float mnew = fmaxf(mrow[r], mx);
            const float alpha = __expf(mrow[r] - mnew);
            mrow[r] = mnew;
            float rs = 0.0f;
            #pragma unroll
            for (int nt = 0; nt < 4; ++nt) {
                s[nt][r] = __expf(s[nt][r] - mnew);
                rs += s[nt][r];
            }
            rs += __shfl_xor(rs, 1, 16);
            rs += __shfl_xor(rs, 2, 16);
            rs += __shfl_xor(rs, 4, 16);
            rs += __shfl_xor(rs, 8, 16);
            lrow[r] = lrow[r] * alpha + rs;
            #pragma unroll
            for (int et = 0; et < 4; ++et) accO[et][r] *= alpha;
        }

        // ---- P (bf16) to wave-private swizzled LDS strip [q][key]
        #pragma unroll
        for (int r = 0; r < 4; ++r) {
            const int qrow = (h4 << 2) + r;
            const int swz = (qrow & 7) << 3;
            #pragma unroll
            for (int nt = 0; nt < 4; ++nt)
                pws[qrow * 64 + ((nt * 16 + c15) ^ swz)] = (short)f2bf(s[nt][r]);
        }

        // ---- O += P V : A-frag rows q=c15, B-frag cols e=et*16+c15
        #pragma unroll
        for (int c = 0; c < 2; ++c) {
            const int kof = (c << 5) + (h4 << 3);
            const short8 pa = *(const short8*)&pws[c15 * 64 + (kof ^ ((c15 & 7) << 3))];
            #pragma unroll
            for (int et = 0; et < 4; ++et) {
                const int e = et * 16 + c15;
                const short8 vb = *(const short8*)&Vs[e * 64 + (kof ^ ((e & 7) << 3))];
                accO[et] = __builtin_amdgcn_mfma_f32_16x16x32_bf16(pa, vb, accO[et], 0, 0, 0);
            }
        }
    }

    // ---- epilogue: normalize, write bf16 y [B,S,D]
    const int bq = bh >> 4, hh = bh & 15;
    #pragma unroll
    for (int r = 0; r < 4; ++r) {
        const int qrow = q0 + w * 16 + (h4 << 2) + r;
        const float inv = 1.0f / lrow[r];
        #pragma unroll
        for (int et = 0; et < 4; ++et)
            yb[((size_t)(bq * S_LEN + qrow)) * DMODEL + hh * HD + et * 16 + c15] =
                (short)f2bf(accO[et][r] * inv);
    }
}

// ---------------------------------------------------------------------------
// Workspace (38 MB): [0,8M) q bf16 | [8,16M) k bf16 | [16,24M) v^T bf16
//   [24,32M) xb (cast->gemm1) / yb (attn->gemm2)  — disjoint in time
//   [32,40M) wab (cast->gemm1) / wpb (cast->gemm2) — disjoint in time
// ---------------------------------------------------------------------------
extern "C" void kernel_launch(void* const* d_in, const int* in_sizes, int n_in,
                              void* d_out, int out_size, void* d_ws, size_t ws_size,
                              hipStream_t stream) {
    const float* x      = (const float*)d_in[0];
    const float* w_attn = (const float*)d_in[1];
    const float* b_attn = (const float*)d_in[2];
    const float* w_proj = (const float*)d_in[3];
    const float* b_proj = (const float*)d_in[4];
    float* out = (float*)d_out;

    const int B = 2;
    const int M = B * S_LEN;
    const size_t x_elems  = (size_t)M * DMODEL;
    const size_t wa_elems = (size_t)3 * DMODEL * DMODEL;
    const size_t wp_elems = (size_t)DMODEL * DMODEL;

    char* wsb = (char*)d_ws;
    short* qw  = (short*)(wsb);
    short* kw  = (short*)(wsb + (8u << 20));
    short* vtw = (short*)(wsb + (16u << 20));
    short* xb  = (short*)(wsb + (24u << 20));
    short* yb  = (short*)(wsb + (24u << 20));
    short* wab = (short*)(wsb + (32u << 20));
    short* wpb = (short*)(wsb + (32u << 20));

    cast_f32_bf16<<<dim3((int)(x_elems  / 8 / 256)), 256, 0, stream>>>(x, xb, (int)(x_elems / 8));
    cast_f32_bf16<<<dim3((int)(wa_elems / 8 / 256)), 256, 0, stream>>>(w_attn, wab, (int)(wa_elems / 8));

    dim3 g1(3 * DMODEL / 128, M / 128);
    gemm_mfma<true><<<g1, 256, 0, stream>>>(xb, wab, b_attn, nullptr,
                                            3 * DMODEL, DMODEL, qw, kw, vtw);

    cast_f32_bf16<<<dim3((int)(wp_elems / 8 / 256)), 256, 0, stream>>>(w_proj, wpb, (int)(wp_elems / 8));

    flash_attn_mfma<<<dim3(B * NHEAD * (S_LEN / 64)), 256, 0, stream>>>(qw, kw, vtw, yb);

    dim3 g3(DMODEL / 128, M / 128);
    gemm_mfma<false><<<g3, 256, 0, stream>>>(yb, wpb, b_proj, out,
                                             DMODEL, DMODEL,
                                             nullptr, nullptr, nullptr);
}

// Round 7
// 200.699 us; speedup vs baseline: 3.3799x; 1.3917x over previous
//
#include <hip/hip_runtime.h>
#include <hip/hip_bf16.h>

#define S_LEN 2048
#define DMODEL 1024
#define NHEAD 16
#define HD 64

typedef short short8 __attribute__((ext_vector_type(8)));
typedef short short4_t __attribute__((ext_vector_type(4)));
typedef float f32x4 __attribute__((ext_vector_type(4)));

// fp32 -> bf16 (RNE) bit-level
__device__ inline unsigned short f2bf(float f) {
    union { float f; unsigned int u; } c;
    c.f = f;
    unsigned int r = c.u + 0x7fffu + ((c.u >> 16) & 1u);
    return (unsigned short)(r >> 16);
}

// ---------------------------------------------------------------------------
// Bulk cast fp32 -> bf16
// ---------------------------------------------------------------------------
__global__ __launch_bounds__(256) void cast_f32_bf16(
    const float* __restrict__ in, short* __restrict__ out, int n8)
{
    int i = blockIdx.x * 256 + threadIdx.x;
    if (i < n8) {
        float4 a = ((const float4*)in)[2 * i];
        float4 b = ((const float4*)in)[2 * i + 1];
        short8 o;
        o[0] = (short)f2bf(a.x); o[1] = (short)f2bf(a.y);
        o[2] = (short)f2bf(a.z); o[3] = (short)f2bf(a.w);
        o[4] = (short)f2bf(b.x); o[5] = (short)f2bf(b.y);
        o[6] = (short)f2bf(b.z); o[7] = (short)f2bf(b.w);
        ((short8*)out)[i] = o;
    }
}

// ---------------------------------------------------------------------------
// bf16 MFMA GEMM (validated r4/r5): C = A @ W^T + bias.
// BM=BN=128, BK=64, 4 waves 2x2, 4x4 16x16x32 fragments per wave.
// A/B k-slots use identical bijection g(h,j)=h*8+j (permutation-invariant).
// C/D mapping (HW-verified): col=lane&15, row=(lane>>4)*4+reg.
// QKV=true: emit bf16 q/k/v all in [B,H,S,hd] layout (natural; V transposed
// later by transpose_v — the r5 in-epilogue V^T scatter cost ~128MB of
// write-allocate traffic at 4KB lane stride).
// ---------------------------------------------------------------------------
template<bool QKV>
__global__ __launch_bounds__(256) void gemm_mfma(
    const short* __restrict__ A, const short* __restrict__ W,
    const float* __restrict__ bias, float* __restrict__ C,
    int N, int K,
    short* __restrict__ qo, short* __restrict__ ko, short* __restrict__ vo)
{
    __shared__ __align__(16) short Ash[128 * 64];
    __shared__ __align__(16) short Bsh[128 * 64];

    const int tid = threadIdx.x;
    const int l = tid & 63;
    const int wid = tid >> 6;
    const int wr = wid >> 1, wc = wid & 1;
    const int n0 = blockIdx.x << 7, m0 = blockIdx.y << 7;

    const short* Abase = A + (size_t)m0 * K;
    const short* Wbase = W + (size_t)n0 * K;

    f32x4 acc[4][4];
    #pragma unroll
    for (int i = 0; i < 4; ++i)
        #pragma unroll
        for (int j = 0; j < 4; ++j)
            acc[i][j] = (f32x4)0.0f;

    short8 sa[4], sb[4];
    int rrow[4], rcol[4];
    #pragma unroll
    for (int i = 0; i < 4; ++i) {
        int chunk = i * 256 + tid;
        rrow[i] = chunk >> 3;
        rcol[i] = (chunk & 7) << 3;
    }

    #pragma unroll
    for (int i = 0; i < 4; ++i) {
        sa[i] = *(const short8*)(Abase + (size_t)rrow[i] * K + rcol[i]);
        sb[i] = *(const short8*)(Wbase + (size_t)rrow[i] * K + rcol[i]);
    }

    const int NT = K >> 6;
    for (int kt = 0; kt < NT; ++kt) {
        __syncthreads();
        #pragma unroll
        for (int i = 0; i < 4; ++i) {
            *(short8*)&Ash[rrow[i] * 64 + rcol[i]] = sa[i];
            *(short8*)&Bsh[rrow[i] * 64 + rcol[i]] = sb[i];
        }
        __syncthreads();
        if (kt + 1 < NT) {
            const int k0 = (kt + 1) << 6;
            #pragma unroll
            for (int i = 0; i < 4; ++i) {
                sa[i] = *(const short8*)(Abase + (size_t)rrow[i] * K + k0 + rcol[i]);
                sb[i] = *(const short8*)(Wbase + (size_t)rrow[i] * K + k0 + rcol[i]);
            }
        }
        #pragma unroll
        for (int kk = 0; kk < 2; ++kk) {
            short8 af[4], bf[4];
            const int kof = kk * 32 + ((l >> 4) << 3);
            #pragma unroll
            for (int mi = 0; mi < 4; ++mi)
                af[mi] = *(const short8*)&Ash[(wr * 64 + mi * 16 + (l & 15)) * 64 + kof];
            #pragma unroll
            for (int ni = 0; ni < 4; ++ni)
                bf[ni] = *(const short8*)&Bsh[(wc * 64 + ni * 16 + (l & 15)) * 64 + kof];
            #pragma unroll
            for (int mi = 0; mi < 4; ++mi)
                #pragma unroll
                for (int ni = 0; ni < 4; ++ni)
                    acc[mi][ni] = __builtin_amdgcn_mfma_f32_16x16x32_bf16(
                        af[mi], bf[ni], acc[mi][ni], 0, 0, 0);
        }
    }

    #pragma unroll
    for (int ni = 0; ni < 4; ++ni) {
        const int col = n0 + wc * 64 + ni * 16 + (l & 15);
        const float bv = bias[col];
        if (QKV) {
            const int part = col >> 10;
            const int h = (col >> 6) & 15;
            const int e = col & 63;
            short* __restrict__ dst = part == 0 ? qo : (part == 1 ? ko : vo);
            #pragma unroll
            for (int mi = 0; mi < 4; ++mi) {
                #pragma unroll
                for (int r = 0; r < 4; ++r) {
                    int row = m0 + wr * 64 + mi * 16 + ((l >> 4) << 2) + r;
                    int b = row >> 11, s = row & (S_LEN - 1);
                    dst[((size_t)(b * NHEAD + h) * S_LEN + s) * HD + e] =
                        (short)f2bf(acc[mi][ni][r] + bv);
                }
            }
        } else {
            #pragma unroll
            for (int mi = 0; mi < 4; ++mi) {
                #pragma unroll
                for (int r = 0; r < 4; ++r) {
                    int row = m0 + wr * 64 + mi * 16 + ((l >> 4) << 2) + r;
                    C[(size_t)row * N + col] = acc[mi][ni][r] + bv;
                }
            }
        }
    }
}

// ---------------------------------------------------------------------------
// V transpose: [bh][s][64] -> [bh][64][s], 64x64 LDS tiles, coalesced
// short8 on both global sides. Pad row to 72 shorts (144B): 16B-aligned rows,
// 4-bank shift per row -> transposed scalar reads conflict-free-ish.
// ---------------------------------------------------------------------------
__global__ __launch_bounds__(256) void transpose_v(
    const short* __restrict__ vin, short* __restrict__ vout)
{
    __shared__ short t[64][72];
    const int tid = threadIdx.x;
    const int bh = blockIdx.x >> 5;
    const int s0 = (blockIdx.x & 31) << 6;
    const size_t ibase = (size_t)bh * S_LEN * HD;
    const size_t obase = (size_t)bh * HD * S_LEN;
    const int r = tid >> 3, c8 = (tid & 7) << 3;

    #pragma unroll
    for (int p = 0; p < 2; ++p) {
        short8 v = *(const short8*)&vin[ibase + (size_t)(s0 + r + p * 32) * HD + c8];
        *(short8*)&t[r + p * 32][c8] = v;
    }
    __syncthreads();
    #pragma unroll
    for (int p = 0; p < 2; ++p) {
        const int e = r + p * 32;
        short8 o;
        #pragma unroll
        for (int i = 0; i < 8; ++i) o[i] = t[c8 + i][e];
        *(short8*)&vout[obase + (size_t)e * S_LEN + s0 + c8] = o;
    }
}

// ---------------------------------------------------------------------------
// MFMA flash attention v2, causal, bf16 in / fp32 softmax+accum.
// Block = 64 q-rows; 4 waves, wave w owns q-rows w*16..w*16+15.
// LPT: qt = 31 - bid/32 (longest blocks dispatch first -> no tail).
// SWAPPED QK^T: mfma(K,Q) -> D col=lane&15=q, so each lane owns one q-row
// with 16 S-values in registers (keys nt*16+h4*4+r). Softmax = in-lane
// reduce + 2 shfl_xor (lanes q, q+16, q+32, q+48 share a q-row's keys).
// P never touches LDS: fed to PV as B-operand in registers using the
// k-bijection g_c(h4,j)=32c+(j>=4)*16+h4*4+(j&3) on BOTH P and V
// (permutation-invariance of the shared-k MFMA dot product, HW-validated).
// PV: mfma(V^T, P) -> O col=q (lane-local with m,l state), rows=e.
// K/V staged in XOR-swizzled LDS (16B slot ^= row&7): K read as b128,
// V read as 2x b64 per fragment.
// ---------------------------------------------------------------------------
__global__ __launch_bounds__(256) void flash_attn_mfma(
    const short* __restrict__ q, const short* __restrict__ k,
    const short* __restrict__ vt, short* __restrict__ yb)
{
    __shared__ __align__(16) short Ks[64 * 64];   // [key][kdim] swizzled
    __shared__ __align__(16) short Vs[64 * 64];   // [e][key]   swizzled

    const int tid = threadIdx.x;
    const int l = tid & 63;
    const int w = tid >> 6;
    const int h4 = l >> 4;
    const int c15 = l & 15;
    const int bid = blockIdx.x;
    const int qt = 31 - (bid >> 5);      // longest-first (LPT)
    const int bh = bid & 31;
    const int q0 = qt << 6;
    const int myq = q0 + (w << 4) + c15;

    const size_t kbase = (size_t)bh * S_LEN * HD;   // q,k: [bh][s][e]
    const size_t vbase = (size_t)bh * HD * S_LEN;   // vt:  [bh][e][s]

    // Q fragments: this lane's q-row, k-chunks c*32 + h4*8
    short8 qf[2];
    {
        const short* qrow = q + kbase + (size_t)myq * HD;
        qf[0] = *(const short8*)(qrow + (h4 << 3));
        qf[1] = *(const short8*)(qrow + 32 + (h4 << 3));
    }

    f32x4 accO[4];   // O[q=c15][e = et*16 + h4*4 + r]
    #pragma unroll
    for (int i = 0; i < 4; ++i) accO[i] = (f32x4)0.0f;
    float mr = -1e30f, lr = 0.0f;

    const int srow0 = tid >> 3, scol = tid & 7;
    short8 kreg[2], vreg[2];
    #pragma unroll
    for (int p = 0; p < 2; ++p) {
        kreg[p] = *(const short8*)(k + kbase + (size_t)(srow0 + p * 32) * HD + scol * 8);
        vreg[p] = *(const short8*)(vt + vbase + (size_t)(srow0 + p * 32) * S_LEN + scol * 8);
    }

    const int ntiles = qt + 1;
    for (int t = 0; t < ntiles; ++t) {
        __syncthreads();
        #pragma unroll
        for (int p = 0; p < 2; ++p) {
            const int row = srow0 + p * 32;
            const int sc = (scol ^ (row & 7)) << 3;
            *(short8*)&Ks[row * 64 + sc] = kreg[p];
            *(short8*)&Vs[row * 64 + sc] = vreg[p];
        }
        __syncthreads();
        if (t + 1 < ntiles) {
            const int kn = (t + 1) << 6;
            #pragma unroll
            for (int p = 0; p < 2; ++p) {
                kreg[p] = *(const short8*)(k + kbase + (size_t)(kn + srow0 + p * 32) * HD + scol * 8);
                vreg[p] = *(const short8*)(vt + vbase + (size_t)(srow0 + p * 32) * S_LEN + kn + scol * 8);
            }
        }

        // ---- S^T = K Q^T : lane holds S[q=c15][key = nt*16 + h4*4 + r]
        f32x4 sacc[4];
        #pragma unroll
        for (int nt = 0; nt < 4; ++nt) sacc[nt] = (f32x4)0.0f;
        #pragma unroll
        for (int c = 0; c < 2; ++c) {
            const int kof = (c << 5) + (h4 << 3);
            #pragma unroll
            for (int nt = 0; nt < 4; ++nt) {
                const int keyrow = nt * 16 + c15;
                const short8 kf = *(const short8*)&Ks[keyrow * 64 + (kof ^ ((keyrow & 7) << 3))];
                sacc[nt] = __builtin_amdgcn_mfma_f32_16x16x32_bf16(kf, qf[c], sacc[nt], 0, 0, 0);
            }
        }

        // ---- scale + causal mask (diag tile only)
        float p16[16];
        const bool diag = (t == qt);
        #pragma unroll
        for (int nt = 0; nt < 4; ++nt)
            #pragma unroll
            for (int r = 0; r < 4; ++r) {
                float v = sacc[nt][r] * 0.125f;   // 1/sqrt(64)
                if (diag && (nt * 16 + (h4 << 2) + r > (w << 4) + c15))
                    v = -1e30f;
                p16[nt * 4 + r] = v;
            }

        // ---- online softmax, lane-local q-row; reduce across h4 groups
        float mx = p16[0];
        #pragma unroll
        for (int i = 1; i < 16; ++i) mx = fmaxf(mx, p16[i]);
        mx = fmaxf(mx, __shfl_xor(mx, 16, 64));
        mx = fmaxf(mx, __shfl_xor(mx, 32, 64));
        const float mnew = fmaxf(mr, mx);
        const float alpha = __expf(mr - mnew);
        mr = mnew;
        float rs = 0.0f;
        #pragma unroll
        for (int i = 0; i < 16; ++i) {
            p16[i] = __expf(p16[i] - mnew);
            rs += p16[i];
        }
        rs += __shfl_xor(rs, 16, 64);
        rs += __shfl_xor(rs, 32, 64);
        lr = lr * alpha + rs;
        #pragma unroll
        for (int et = 0; et < 4; ++et) accO[et] *= alpha;

        // ---- P bf16 B-fragments, in registers (k-order g_c)
        short8 pb[2];
        #pragma unroll
        for (int c = 0; c < 2; ++c)
            #pragma unroll
            for (int i = 0; i < 8; ++i)
                pb[c][i] = (short)f2bf(p16[8 * c + i]);

        // ---- O += V^T x P : A = V^T rows e (2x b64 per frag), B = P regs
        #pragma unroll
        for (int c = 0; c < 2; ++c) {
            const int ch = (c << 2) + (h4 >> 1);
            const int halfo = (h4 & 1) << 2;
            #pragma unroll
            for (int et = 0; et < 4; ++et) {
                const int e = (et << 4) + c15;
                const int rb = e << 6;
                const int sw = e & 7;
                const short4_t va = *(const short4_t*)&Vs[rb + ((ch ^ sw) << 3) + halfo];
                const short4_t vb = *(const short4_t*)&Vs[rb + (((ch + 2) ^ sw) << 3) + halfo];
                const short8 vf = {va[0], va[1], va[2], va[3], vb[0], vb[1], vb[2], vb[3]};
                accO[et] = __builtin_amdgcn_mfma_f32_16x16x32_bf16(vf, pb[c], accO[et], 0, 0, 0);
            }
        }
    }

    // ---- epilogue: normalize (lane-local l), write bf16 y [B,S,D]
    const int bq = bh >> 4, hh = bh & 15;
    const float inv = 1.0f / lr;
    short* orow = yb + ((size_t)bq * S_LEN + myq) * DMODEL + hh * HD;
    #pragma unroll
    for (int et = 0; et < 4; ++et) {
        short4_t o;
        #pragma unroll
        for (int r = 0; r < 4; ++r) o[r] = (short)f2bf(accO[et][r] * inv);
        *(short4_t*)&orow[(et << 4) + (h4 << 2)] = o;
    }
}

// ---------------------------------------------------------------------------
// Workspace (46 MB):
//   [ 0, 8M) q bf16 [B,H,S,hd]     [ 8,16M) k bf16     [16,24M) v bf16
//   [24,32M) v^T bf16 [B,H,hd,S]
//   [32,40M) xb (cast->gemm1) / yb (attn->gemm2)   — disjoint in time
//   [40,46M) wab (cast->gemm1) / wpb (cast->gemm2) — disjoint in time
// ---------------------------------------------------------------------------
extern "C" void kernel_launch(void* const* d_in, const int* in_sizes, int n_in,
                              void* d_out, int out_size, void* d_ws, size_t ws_size,
                              hipStream_t stream) {
    const float* x      = (const float*)d_in[0];
    const float* w_attn = (const float*)d_in[1];
    const float* b_attn = (const float*)d_in[2];
    const float* w_proj = (const float*)d_in[3];
    const float* b_proj = (const float*)d_in[4];
    float* out = (float*)d_out;

    const int B = 2;
    const int M = B * S_LEN;
    const size_t x_elems  = (size_t)M * DMODEL;
    const size_t wa_elems = (size_t)3 * DMODEL * DMODEL;
    const size_t wp_elems = (size_t)DMODEL * DMODEL;

    char* wsb = (char*)d_ws;
    short* qw  = (short*)(wsb);
    short* kw  = (short*)(wsb + (8u << 20));
    short* vw  = (short*)(wsb + (16u << 20));
    short* vtw = (short*)(wsb + (24u << 20));
    short* xb  = (short*)(wsb + (32u << 20));
    short* yb  = (short*)(wsb + (32u << 20));
    short* wab = (short*)(wsb + (40u << 20));
    short* wpb = (short*)(wsb + (40u << 20));

    cast_f32_bf16<<<dim3((int)(x_elems  / 8 / 256)), 256, 0, stream>>>(x, xb, (int)(x_elems / 8));
    cast_f32_bf16<<<dim3((int)(wa_elems / 8 / 256)), 256, 0, stream>>>(w_attn, wab, (int)(wa_elems / 8));

    dim3 g1(3 * DMODEL / 128, M / 128);
    gemm_mfma<true><<<g1, 256, 0, stream>>>(xb, wab, b_attn, nullptr,
                                            3 * DMODEL, DMODEL, qw, kw, vw);

    cast_f32_bf16<<<dim3((int)(wp_elems / 8 / 256)), 256, 0, stream>>>(w_proj, wpb, (int)(wp_elems / 8));
    transpose_v<<<dim3(2 * NHEAD * (S_LEN / 64)), 256, 0, stream>>>(vw, vtw);

    flash_attn_mfma<<<dim3(2 * NHEAD * (S_LEN / 64)), 256, 0, stream>>>(qw, kw, vtw, yb);

    dim3 g3(DMODEL / 128, M / 128);
    gemm_mfma<false><<<g3, 256, 0, stream>>>(yb, wpb, b_proj, out,
                                             DMODEL, DMODEL,
                                             nullptr, nullptr, nullptr);
}